// Round 1
// baseline (194.105 us; speedup 1.0000x reference)
//
#include <hip/hip_runtime.h>
#include <hip/hip_bf16.h>

// Problem constants (fixed by the reference's setup_inputs)
#define N_PRE 8192
#define N_CUR 16384
#define KNN   8

// ---------- helpers ----------
__device__ __forceinline__ unsigned long long shfl_u64(unsigned long long x, int srclane) {
    int lo = __shfl((int)(unsigned int)x, srclane);
    int hi = __shfl((int)(unsigned int)(x >> 32), srclane);
    return (((unsigned long long)(unsigned int)hi) << 32) | (unsigned int)lo;
}

__device__ __forceinline__ unsigned long long shfl_up1_u64(unsigned long long x) {
    int lo = __shfl_up((int)(unsigned int)x, 1);
    int hi = __shfl_up((int)(unsigned int)(x >> 32), 1);
    return (((unsigned long long)(unsigned int)hi) << 32) | (unsigned int)lo;
}

// ---------- Kernel A: cur2pre = argmin over pre of dist(cur_j, pre_i) ----------
// grid: (N_CUR/256, NSEG), block: 256. Each thread owns one cur point and scans
// one segment of pre points staged in LDS; segments merged via u64 atomicMin on
// packed (dist_bits << 32 | pre_idx)  ->  tie breaks to lower index = argmin.
#define NSEG_A   16
#define SEG_PTS  (N_PRE / NSEG_A)   // 512

__global__ __launch_bounds__(256) void cur2pre_kernel(
        const float* __restrict__ pre, const float* __restrict__ cur,
        unsigned long long* __restrict__ c2p) {
    __shared__ float4 sp[SEG_PTS];
    const int t   = threadIdx.x;
    const int seg = blockIdx.y;
    const int base = seg * SEG_PTS;

    for (int k = t; k < SEG_PTS; k += 256) {
        int p = base + k;
        sp[k] = make_float4(pre[p], pre[N_PRE + p], pre[2 * N_PRE + p], 0.f);
    }
    __syncthreads();

    const int j = blockIdx.x * 256 + t;
    const float cx = cur[j], cy = cur[N_CUR + j], cz = cur[2 * N_CUR + j];

    float best = __int_as_float(0x7F800000);  // +inf
    int bidx = base;
#pragma unroll 4
    for (int k = 0; k < SEG_PTS; ++k) {
        float4 p = sp[k];
        float dx = cx - p.x, dy = cy - p.y, dz = cz - p.z;
        float d = fmaf(dx, dx, fmaf(dy, dy, dz * dz));
        if (d < best) { best = d; bidx = base + k; }   // strict < keeps lowest idx
    }
    unsigned long long packed =
        (((unsigned long long)__float_as_uint(best)) << 32) | (unsigned int)bidx;
    atomicMin(&c2p[j], packed);
}

// ---------- Kernel B: per pre point, top-8 nearest cur + masked sum ----------
// One wave per pre point; 16 waves/block share an LDS tile of cur points.
// Wave-shared top-8: lanes 0..7 hold a sorted (ascending) list of packed u64
// (dist_bits<<32 | cur_idx). Fast path per 64 candidates: cmp + ballot only.
#define TILE_B 2048

__global__ __launch_bounds__(1024) void knn_finalize_kernel(
        const float* __restrict__ pre, const float* __restrict__ cur,
        const float* __restrict__ ups,
        const unsigned long long* __restrict__ c2p,
        float* __restrict__ out) {
    __shared__ float4 sc[TILE_B];
    const int tid  = threadIdx.x;
    const int lane = tid & 63;
    const int w    = tid >> 6;                 // 0..15
    const int i    = blockIdx.x * 16 + w;      // pre point for this wave

    const float px = pre[i], py = pre[N_PRE + i], pz = pre[2 * N_PRE + i];

    unsigned long long list = ~0ull;   // lanes 0..7: sorted top-8 (others: junk)
    unsigned long long t8   = ~0ull;   // current 8th smallest (wave-uniform value)

    for (int tile = 0; tile < N_CUR; tile += TILE_B) {
        __syncthreads();
        for (int k = tid; k < TILE_B; k += 1024) {
            int j = tile + k;
            sc[k] = make_float4(cur[j], cur[N_CUR + j], cur[2 * N_CUR + j], 0.f);
        }
        __syncthreads();

        for (int s = 0; s < TILE_B; s += 64) {
            float4 c = sc[s + lane];
            float dx = c.x - px, dy = c.y - py, dz = c.z - pz;
            float dsq = fmaf(dx, dx, fmaf(dy, dy, dz * dz));
            unsigned long long v =
                (((unsigned long long)__float_as_uint(dsq)) << 32) |
                (unsigned int)(tile + s + lane);

            unsigned long long m = __ballot(v < t8);
            while (m) {                       // m is wave-uniform
                int src = __ffsll((long long)m) - 1;
                m &= m - 1;
                unsigned long long v2 = shfl_u64(v, src);
                unsigned long long up = shfl_up1_u64(list);
                if (lane == 0) up = 0ull;     // nothing below lane 0
                // shift-insert into ascending sorted list held on lanes 0..7
                list = (v2 < up) ? up : ((v2 < list) ? v2 : list);
                t8 = shfl_u64(list, 7);
            }
        }
    }

    // finalize: mask by (cur2pre[j] == i), sum sqrt(dsq), divide by upsample
    float contrib = 0.f;
    if (lane < KNN) {
        unsigned int j   = (unsigned int)(list & 0xFFFFFFFFull);
        float        dsq = __uint_as_float((unsigned int)(list >> 32));
        unsigned int cidx = (unsigned int)(c2p[j] & 0xFFFFFFFFull);
        contrib = (cidx == (unsigned int)i) ? sqrtf(dsq) : 0.f;
    }
    contrib += __shfl_xor(contrib, 1);
    contrib += __shfl_xor(contrib, 2);
    contrib += __shfl_xor(contrib, 4);
    if (lane == 0) out[i] = contrib / ups[i];
}

// ---------- launch ----------
extern "C" void kernel_launch(void* const* d_in, const int* in_sizes, int n_in,
                              void* d_out, int out_size, void* d_ws, size_t ws_size,
                              hipStream_t stream) {
    const float* pre = (const float*)d_in[0];   // (1,3,8192)
    const float* cur = (const float*)d_in[1];   // (1,3,16384)
    const float* ups = (const float*)d_in[2];   // (1,8192)
    float* out = (float*)d_out;                 // (1,8192)

    unsigned long long* c2p = (unsigned long long*)d_ws;  // N_CUR u64

    // init packed argmin buffer to 0xFF.. so atomicMin works
    hipMemsetAsync(c2p, 0xFF, N_CUR * sizeof(unsigned long long), stream);

    dim3 gA(N_CUR / 256, NSEG_A);
    cur2pre_kernel<<<gA, 256, 0, stream>>>(pre, cur, c2p);

    knn_finalize_kernel<<<N_PRE / 16, 1024, 0, stream>>>(pre, cur, ups, c2p, out);
}

// Round 3
// 174.717 us; speedup vs baseline: 1.1110x; 1.1110x over previous
//
#include <hip/hip_runtime.h>

// Problem constants (fixed by reference setup_inputs)
#define N_PRE 8192
#define N_CUR 16384
#define KNN   8

// Workspace layout (bytes):
//   [0,       128K) : c2p  u64[N_CUR]    packed (dist_bits<<32 | pre_idx)
//   [128K,    256K) : pre4 float4[N_PRE] (px,py,pz,0)
//   [256K,    512K) : cur4 float4[N_CUR] (cx,cy,cz,0)

#define INF_BITS 0x7F800000u   // +inf: sentinel for empty top-8 slots.
// NOTE: must NOT be 0xFFFFFFFF — that's a NaN pattern, and the float
// threshold compare (d < t8) then fails forever (round-2 bug).

// ---------- prep: pack coords as float4, init argmin buffer ----------
__global__ __launch_bounds__(256) void prep_kernel(
        const float* __restrict__ pre, const float* __restrict__ cur,
        float4* __restrict__ pre4, float4* __restrict__ cur4,
        unsigned long long* __restrict__ c2p) {
    int i = blockIdx.x * 256 + threadIdx.x;
    if (i < N_CUR) {
        cur4[i] = make_float4(cur[i], cur[N_CUR + i], cur[2 * N_CUR + i], 0.f);
        c2p[i] = ~0ull;
    }
    if (i < N_PRE) {
        pre4[i] = make_float4(pre[i], pre[N_PRE + i], pre[2 * N_PRE + i], 0.f);
    }
}

// ---------- Kernel A: cur2pre argmin ----------
#define NSEG_A  16
#define SEG_PTS (N_PRE / NSEG_A)   // 512

__global__ __launch_bounds__(256) void cur2pre_kernel(
        const float4* __restrict__ pre4, const float4* __restrict__ cur4,
        unsigned long long* __restrict__ c2p) {
    const int j = blockIdx.x * 256 + threadIdx.x;
    const int base = blockIdx.y * SEG_PTS;
    const float4 c = cur4[j];

    float best = __int_as_float(0x7F800000);  // +inf
    int bi = 0;
#pragma unroll 8
    for (int k = 0; k < SEG_PTS; ++k) {
        float4 p = pre4[base + k];            // wave-uniform -> scalar load
        float dx = c.x - p.x, dy = c.y - p.y, dz = c.z - p.z;
        float d = fmaf(dx, dx, fmaf(dy, dy, dz * dz));
        if (d < best) { best = d; bi = k; }   // strict < keeps lowest idx
    }
    unsigned long long packed =
        (((unsigned long long)__float_as_uint(best)) << 32) | (unsigned)(base + bi);
    atomicMin(&c2p[j], packed);
}

// ---------- Kernel B: per-pre top-8 + masked mean ----------
// Wave handles P=2 pre points; 16 waves/block share one LDS tile of cur4, so
// each ds_read_b128 feeds 2 distance evals. Fast path per candidate per pre:
// 3 sub + 3 fma + v_cmp(=ballot). Top-8 lives on lanes 0..7 as (u32 dist-bits,
// u32 idx), ascending; rare shfl-shift insert with re-ballot pruning.
#define TILE_B 2048

__device__ __forceinline__ unsigned shfl_u32(unsigned x, int src) {
    return (unsigned)__shfl((int)x, src);
}
__device__ __forceinline__ unsigned shfl_up1_u32(unsigned x) {
    return (unsigned)__shfl_up((int)x, 1);
}

__global__ __launch_bounds__(1024) void knn_finalize_kernel(
        const float4* __restrict__ pre4, const float4* __restrict__ cur4,
        const float* __restrict__ ups,
        const unsigned long long* __restrict__ c2p,
        float* __restrict__ out) {
    __shared__ float4 sc[TILE_B];
    const int tid  = threadIdx.x;
    const int lane = tid & 63;
    const int w    = tid >> 6;                 // 0..15
    const int i0   = blockIdx.x * 32 + w * 2;  // this wave's two pre points
    const int i1   = i0 + 1;

    const float4 p0 = pre4[i0];
    const float4 p1 = pre4[i1];

    // lanes 0..7: sorted (ascending) top-8 as (dist bits, cur idx)
    unsigned ld0 = INF_BITS, li0 = 0u;
    unsigned ld1 = INF_BITS, li1 = 0u;
    float t80 = __int_as_float(0x7F800000);    // current 8th-smallest dist
    float t81 = t80;

    for (int tile = 0; tile < N_CUR; tile += TILE_B) {
        __syncthreads();
        for (int k = tid; k < TILE_B; k += 1024) sc[k] = cur4[tile + k];
        __syncthreads();

#pragma unroll 4
        for (int s = 0; s < TILE_B; s += 64) {
            float4 c = sc[s + lane];
            float dx0 = c.x - p0.x, dy0 = c.y - p0.y, dz0 = c.z - p0.z;
            float d0  = fmaf(dx0, dx0, fmaf(dy0, dy0, dz0 * dz0));
            float dx1 = c.x - p1.x, dy1 = c.y - p1.y, dz1 = c.z - p1.z;
            float d1  = fmaf(dx1, dx1, fmaf(dy1, dy1, dz1 * dz1));
            int jj = tile + s + lane;

            unsigned long long m0 = __ballot(d0 < t80);
            while (m0) {
                int src = __ffsll(m0) - 1;
                unsigned kd = shfl_u32(__float_as_uint(d0), src);
                unsigned kj = shfl_u32((unsigned)jj, src);
                unsigned ud = shfl_up1_u32(ld0);
                unsigned uj = shfl_up1_u32(li0);
                if (lane == 0) ud = 0u;        // nothing shifts in below lane 0
                bool hi = kd < ud, lo = kd < ld0;
                ld0 = hi ? ud : (lo ? kd : ld0);
                li0 = hi ? uj : (lo ? kj : li0);
                t80 = __uint_as_float(shfl_u32(ld0, 7));
                m0 = (m0 & (m0 - 1)) & __ballot(d0 < t80);  // prune survivors
            }

            unsigned long long m1 = __ballot(d1 < t81);
            while (m1) {
                int src = __ffsll(m1) - 1;
                unsigned kd = shfl_u32(__float_as_uint(d1), src);
                unsigned kj = shfl_u32((unsigned)jj, src);
                unsigned ud = shfl_up1_u32(ld1);
                unsigned uj = shfl_up1_u32(li1);
                if (lane == 0) ud = 0u;
                bool hi = kd < ud, lo = kd < ld1;
                ld1 = hi ? ud : (lo ? kd : ld1);
                li1 = hi ? uj : (lo ? kj : li1);
                t81 = __uint_as_float(shfl_u32(ld1, 7));
                m1 = (m1 & (m1 - 1)) & __ballot(d1 < t81);
            }
        }
    }

    // finalize: lanes 0..7 handle pre i0's list, lanes 8..15 handle i1's
    unsigned ja = shfl_u32(li0, lane & 7);
    unsigned jb = shfl_u32(li1, lane & 7);
    unsigned j  = (lane < 8) ? ja : jb;

    float contrib = 0.f;
    if (lane < 16) {
        float4 c = cur4[j];
        float px = (lane < 8) ? p0.x : p1.x;
        float py = (lane < 8) ? p0.y : p1.y;
        float pz = (lane < 8) ? p0.z : p1.z;
        float dx = c.x - px, dy = c.y - py, dz = c.z - pz;
        float dsq = fmaf(dx, dx, fmaf(dy, dy, dz * dz));
        unsigned owner = ((const unsigned*)c2p)[2u * j];   // low word = pre idx
        unsigned iexp  = (lane < 8) ? (unsigned)i0 : (unsigned)i1;
        contrib = (owner == iexp) ? sqrtf(dsq) : 0.f;
    }
    contrib += __shfl_xor(contrib, 1);
    contrib += __shfl_xor(contrib, 2);
    contrib += __shfl_xor(contrib, 4);
    if (lane == 0) out[i0] = contrib / ups[i0];
    if (lane == 8) out[i1] = contrib / ups[i1];
}

// ---------- launch ----------
extern "C" void kernel_launch(void* const* d_in, const int* in_sizes, int n_in,
                              void* d_out, int out_size, void* d_ws, size_t ws_size,
                              hipStream_t stream) {
    const float* pre = (const float*)d_in[0];   // (1,3,8192)
    const float* cur = (const float*)d_in[1];   // (1,3,16384)
    const float* ups = (const float*)d_in[2];   // (1,8192)
    float* out = (float*)d_out;                 // (1,8192)

    char* ws = (char*)d_ws;
    unsigned long long* c2p = (unsigned long long*)ws;           // 128 KB
    float4* pre4 = (float4*)(ws + 131072);                       // 128 KB
    float4* cur4 = (float4*)(ws + 262144);                       // 256 KB

    prep_kernel<<<N_CUR / 256, 256, 0, stream>>>(pre, cur, pre4, cur4, c2p);

    dim3 gA(N_CUR / 256, NSEG_A);
    cur2pre_kernel<<<gA, 256, 0, stream>>>(pre4, cur4, c2p);

    knn_finalize_kernel<<<N_PRE / 32, 1024, 0, stream>>>(pre4, cur4, ups, c2p, out);
}

// Round 4
// 142.774 us; speedup vs baseline: 1.3595x; 1.2237x over previous
//
#include <hip/hip_runtime.h>

// Problem constants (fixed by reference setup_inputs)
#define N_PRE 8192
#define N_CUR 16384
#define KNN   8

// Workspace layout (bytes):
//   [0,    64K) : c2p  u32[N_CUR]     nearest-pre index per cur point
//   [64K, 192K) : pre4 float4[N_PRE]  (-2px, -2py, -2pz, |p|^2)
//   [192K,448K) : cur4 float4[N_CUR]  ( cx,   cy,   cz,  |c|^2)
//
// Comparator trick: for a fixed query q, ordering by true sqdist equals
// ordering by (|cand|^2 - 2 cand.q)  -> 3 FMA per candidate.
//   A (query=cur, cand=pre): d = pre4.w + pre4.x*cx + pre4.y*cy + pre4.z*cz
//   B (query=pre, cand=cur): d = cur4.w + pre4.x*cx + pre4.y*cy + pre4.z*cz
// d can be NEGATIVE -> use monotone float->u32 key map on (rare) inserts.

#define MAPPED_INF 0xFF800000u  // monotone key of +inf (empty-slot sentinel)

__device__ __forceinline__ unsigned key_of(float d) {
    unsigned b = __float_as_uint(d);
    return b ^ (0x80000000u | (unsigned)((int)b >> 31));
}
__device__ __forceinline__ float float_of_key(unsigned k) {
    unsigned b = (k & 0x80000000u) ? (k ^ 0x80000000u) : ~k;
    return __uint_as_float(b);
}
__device__ __forceinline__ unsigned shfl_u32(unsigned x, int src) {
    return (unsigned)__shfl((int)x, src);
}
__device__ __forceinline__ unsigned shfl_up1_u32(unsigned x) {
    return (unsigned)__shfl_up((int)x, 1);
}

// ---------- prep: pack comparator-form coords ----------
__global__ __launch_bounds__(256) void prep_kernel(
        const float* __restrict__ pre, const float* __restrict__ cur,
        float4* __restrict__ pre4, float4* __restrict__ cur4) {
    int i = blockIdx.x * 256 + threadIdx.x;
    if (i < N_CUR) {
        float x = cur[i], y = cur[N_CUR + i], z = cur[2 * N_CUR + i];
        cur4[i] = make_float4(x, y, z, fmaf(x, x, fmaf(y, y, z * z)));
    }
    if (i < N_PRE) {
        float x = pre[i], y = pre[N_PRE + i], z = pre[2 * N_PRE + i];
        pre4[i] = make_float4(-2.f * x, -2.f * y, -2.f * z,
                              fmaf(x, x, fmaf(y, y, z * z)));
    }
}

// ---------- Kernel A: cur2pre argmin ----------
// Wave owns 4 cur points; lanes scan pre candidates from an LDS tile.
// Per-lane branchless running min (strict < keeps lowest idx within the
// lane's ascending-index stream); cross-lane merge via packed-u64 min.
#define TILE_A 2048

__global__ __launch_bounds__(1024) void cur2pre_kernel(
        const float4* __restrict__ pre4, const float4* __restrict__ cur4,
        unsigned* __restrict__ c2p) {
    __shared__ float4 sp[TILE_A];
    const int tid  = threadIdx.x;
    const int lane = tid & 63;
    const int w    = tid >> 6;
    const int j0   = blockIdx.x * 64 + w * 4;   // this wave's 4 cur points

    const float4 c0 = cur4[j0 + 0];
    const float4 c1 = cur4[j0 + 1];
    const float4 c2 = cur4[j0 + 2];
    const float4 c3 = cur4[j0 + 3];

    const float INF = __int_as_float(0x7F800000);
    float b0 = INF, b1 = INF, b2 = INF, b3 = INF;
    int   i0 = 0,   i1 = 0,   i2 = 0,   i3 = 0;

    for (int tile = 0; tile < N_PRE; tile += TILE_A) {
        __syncthreads();
        for (int k = tid; k < TILE_A; k += 1024) sp[k] = pre4[tile + k];
        __syncthreads();

#pragma unroll 4
        for (int s = 0; s < TILE_A; s += 64) {
            float4 q = sp[s + lane];
            int idx = tile + s + lane;
            float d0 = fmaf(q.x, c0.x, fmaf(q.y, c0.y, fmaf(q.z, c0.z, q.w)));
            float d1 = fmaf(q.x, c1.x, fmaf(q.y, c1.y, fmaf(q.z, c1.z, q.w)));
            float d2 = fmaf(q.x, c2.x, fmaf(q.y, c2.y, fmaf(q.z, c2.z, q.w)));
            float d3 = fmaf(q.x, c3.x, fmaf(q.y, c3.y, fmaf(q.z, c3.z, q.w)));
            if (d0 < b0) { b0 = d0; i0 = idx; }
            if (d1 < b1) { b1 = d1; i1 = idx; }
            if (d2 < b2) { b2 = d2; i2 = idx; }
            if (d3 < b3) { b3 = d3; i3 = idx; }
        }
    }

    // cross-lane min with lowest-index tie-break via packed (key<<32 | idx)
    float        bs[4] = {b0, b1, b2, b3};
    int          is[4] = {i0, i1, i2, i3};
#pragma unroll
    for (int t = 0; t < 4; ++t) {
        unsigned long long v =
            (((unsigned long long)key_of(bs[t])) << 32) | (unsigned)is[t];
#pragma unroll
        for (int off = 32; off > 0; off >>= 1) {
            unsigned long long o = __shfl_xor((unsigned long long)v, off);
            v = (o < v) ? o : v;
        }
        if (lane == 0) c2p[j0 + t] = (unsigned)(v & 0xFFFFFFFFull);
    }
}

// ---------- Kernel B: per-pre top-8 + masked mean ----------
// Wave handles P=2 pre points; 16 waves/block share one LDS cur tile.
// Fast path per candidate per pre: 3 FMA + 1 float cmp (the ballot).
// Top-8 on lanes 0..7 as (monotone u32 key, u32 idx), ascending.
#define TILE_B 2048

__global__ __launch_bounds__(1024) void knn_finalize_kernel(
        const float4* __restrict__ pre4, const float4* __restrict__ cur4,
        const float* __restrict__ ups,
        const unsigned* __restrict__ c2p,
        float* __restrict__ out) {
    __shared__ float4 sc[TILE_B];
    const int tid  = threadIdx.x;
    const int lane = tid & 63;
    const int w    = tid >> 6;
    const int i0   = blockIdx.x * 32 + w * 2;
    const int i1   = i0 + 1;

    const float4 p0 = pre4[i0];   // (-2p, |p|^2)
    const float4 p1 = pre4[i1];

    unsigned ld0 = MAPPED_INF, li0 = 0u;
    unsigned ld1 = MAPPED_INF, li1 = 0u;
    float t80 = __int_as_float(0x7F800000);
    float t81 = t80;

    for (int tile = 0; tile < N_CUR; tile += TILE_B) {
        __syncthreads();
        for (int k = tid; k < TILE_B; k += 1024) sc[k] = cur4[tile + k];
        __syncthreads();

#pragma unroll 4
        for (int s = 0; s < TILE_B; s += 64) {
            float4 c = sc[s + lane];
            float d0 = fmaf(p0.x, c.x, fmaf(p0.y, c.y, fmaf(p0.z, c.z, c.w)));
            float d1 = fmaf(p1.x, c.x, fmaf(p1.y, c.y, fmaf(p1.z, c.z, c.w)));
            int jj = tile + s + lane;

            unsigned long long m0 = __ballot(d0 < t80);
            while (m0) {
                int src = __ffsll(m0) - 1;
                float fd = __uint_as_float(shfl_u32(__float_as_uint(d0), src));
                unsigned kd = key_of(fd);
                unsigned kj = shfl_u32((unsigned)jj, src);
                unsigned ud = shfl_up1_u32(ld0);
                unsigned uj = shfl_up1_u32(li0);
                if (lane == 0) ud = 0u;        // nothing shifts in below lane 0
                bool hi = kd < ud, lo = kd < ld0;
                ld0 = hi ? ud : (lo ? kd : ld0);
                li0 = hi ? uj : (lo ? kj : li0);
                t80 = float_of_key(shfl_u32(ld0, 7));
                m0 = (m0 & (m0 - 1)) & __ballot(d0 < t80);
            }

            unsigned long long m1 = __ballot(d1 < t81);
            while (m1) {
                int src = __ffsll(m1) - 1;
                float fd = __uint_as_float(shfl_u32(__float_as_uint(d1), src));
                unsigned kd = key_of(fd);
                unsigned kj = shfl_u32((unsigned)jj, src);
                unsigned ud = shfl_up1_u32(ld1);
                unsigned uj = shfl_up1_u32(li1);
                if (lane == 0) ud = 0u;
                bool hi = kd < ud, lo = kd < ld1;
                ld1 = hi ? ud : (lo ? kd : ld1);
                li1 = hi ? uj : (lo ? kj : li1);
                t81 = float_of_key(shfl_u32(ld1, 7));
                m1 = (m1 & (m1 - 1)) & __ballot(d1 < t81);
            }
        }
    }

    // finalize: lanes 0..7 -> i0's list, lanes 8..15 -> i1's.
    // True distance recomputed in direct form; p recovered exactly (* -0.5).
    unsigned ja = shfl_u32(li0, lane & 7);
    unsigned jb = shfl_u32(li1, lane & 7);
    unsigned j  = (lane < 8) ? ja : jb;

    float contrib = 0.f;
    if (lane < 16) {
        float4 c = cur4[j];
        float px = -0.5f * ((lane < 8) ? p0.x : p1.x);
        float py = -0.5f * ((lane < 8) ? p0.y : p1.y);
        float pz = -0.5f * ((lane < 8) ? p0.z : p1.z);
        float dx = c.x - px, dy = c.y - py, dz = c.z - pz;
        float dsq = fmaf(dx, dx, fmaf(dy, dy, dz * dz));
        unsigned owner = c2p[j];
        unsigned iexp  = (lane < 8) ? (unsigned)i0 : (unsigned)i1;
        contrib = (owner == iexp) ? sqrtf(dsq) : 0.f;
    }
    contrib += __shfl_xor(contrib, 1);
    contrib += __shfl_xor(contrib, 2);
    contrib += __shfl_xor(contrib, 4);
    if (lane == 0) out[i0] = contrib / ups[i0];
    if (lane == 8) out[i1] = contrib / ups[i1];
}

// ---------- launch ----------
extern "C" void kernel_launch(void* const* d_in, const int* in_sizes, int n_in,
                              void* d_out, int out_size, void* d_ws, size_t ws_size,
                              hipStream_t stream) {
    const float* pre = (const float*)d_in[0];   // (1,3,8192)
    const float* cur = (const float*)d_in[1];   // (1,3,16384)
    const float* ups = (const float*)d_in[2];   // (1,8192)
    float* out = (float*)d_out;                 // (1,8192)

    char* ws = (char*)d_ws;
    unsigned* c2p = (unsigned*)ws;                    //  64 KB
    float4*   pre4 = (float4*)(ws + 65536);           // 128 KB
    float4*   cur4 = (float4*)(ws + 65536 + 131072);  // 256 KB

    prep_kernel<<<N_CUR / 256, 256, 0, stream>>>(pre, cur, pre4, cur4);

    cur2pre_kernel<<<N_CUR / 64, 1024, 0, stream>>>(pre4, cur4, c2p);

    knn_finalize_kernel<<<N_PRE / 32, 1024, 0, stream>>>(pre4, cur4, ups, c2p, out);
}